// Round 12
// baseline (97.930 us; speedup 1.0000x reference)
//
#include <hip/hip_runtime.h>
#include <hip/hip_bf16.h>
#include <math.h>

#define Bn   8
#define DIM  128
#define Hs   64
#define Ws   64
#define PADn 3
#define GC   16
#define Gn   8
#define CMID 32    // DIM/RED
#define NW   392   // K*K*G
#define NWP  416   // w2b padded rows

typedef __bf16 bf16x8 __attribute__((ext_vector_type(8)));
typedef float  f32x4  __attribute__((ext_vector_type(4)));
typedef _Float16 h2v  __attribute__((ext_vector_type(2)));
typedef __fp16   fp16x2 __attribute__((ext_vector_type(2)));

__device__ __forceinline__ f32x4 mfma16(bf16x8 a, bf16x8 b, f32x4 c) {
    return __builtin_amdgcn_mfma_f32_16x16x32_bf16(a, b, c, 0, 0, 0);
}

__device__ __forceinline__ __bf16 tobf(float v) {
    __hip_bfloat16 h = __float2bfloat16(v);
    return *reinterpret_cast<__bf16*>(&h);
}

__device__ __forceinline__ unsigned su16(float f) {
    __hip_bfloat16 h = __float2bfloat16(f);
    return (unsigned)*reinterpret_cast<unsigned short*>(&h);
}

__device__ __forceinline__ h2v pk2h(float a, float b) {
    fp16x2 p = __builtin_amdgcn_cvt_pkrtz(a, b);
    return __builtin_bit_cast(h2v, p);
}

// tanh-form gelu
__device__ __forceinline__ float gelu_t(float v) {
    float u = 0.7978845608f * v * fmaf(0.044715f, v * v, 1.0f);
    float t = __builtin_amdgcn_exp2f(fminf(u, 30.f) * 2.885390082f);
    return v * t * __builtin_amdgcn_rcpf(t + 1.0f);
}

// ---------------- K0: convert weights to bf16 (+ permute pw1 K-dim) ----------------
// y_p[pix][j] = y[pix][c(j)], c(j) = g*16 + q + 4m with q=j>>5, g=(j>>2)&7, m=j&3.
__global__ __launch_bounds__(256) void k0_cvt(const float* __restrict__ w1,
        const float* __restrict__ w2,
        const float* __restrict__ pw1, const float* __restrict__ pw2,
        __hip_bfloat16* __restrict__ w1b, __hip_bfloat16* __restrict__ w2b,
        __hip_bfloat16* __restrict__ mw1b, __hip_bfloat16* __restrict__ mw2b) {
    int i = blockIdx.x * 256 + threadIdx.x;   // 32768 threads
    if (i < CMID * DIM) w1b[i] = __float2bfloat16(w1[i]);
    if (i < NWP * CMID)
        w2b[i] = (i < NW * CMID) ? __float2bfloat16(w2[i]) : __float2bfloat16(0.f);
    {
        int f = i >> 7, j = i & 127;
        int qq = j >> 5, gg = (j >> 2) & 7, mm = j & 3;
        mw1b[i] = __float2bfloat16(pw1[f * 128 + gg * 16 + qq + 4 * mm]);
    }
    mw2b[i] = __float2bfloat16(pw2[i]);
}

// ---- K_ALL: 256 threads / 4 waves, fully fused, 1 barrier per group ----
__global__ __launch_bounds__(256) void k_all(const float* __restrict__ x,
        const __hip_bfloat16* __restrict__ w1b, const float* __restrict__ b1v,
        const float* __restrict__ bng, const float* __restrict__ bnb,
        const float* __restrict__ bnm, const float* __restrict__ bnv,
        const __hip_bfloat16* __restrict__ w2b, const float* __restrict__ b2v,
        const float* __restrict__ lng, const float* __restrict__ lnb,
        const __hip_bfloat16* __restrict__ mw1b, const float* __restrict__ mb1,
        const __hip_bfloat16* __restrict__ mw2b, const float* __restrict__ mb2,
        float* __restrict__ out) {
    __shared__ __align__(16) char uni[62480];
    __shared__ float ps[4][64], pss[4][64], mu_s[64], rs_s[64];
    // phase A views
    h2v* xp2   = (h2v*)uni;                                  // [2][8][7][72]  32256 B
    h2v* wgt2  = (h2v*)(uni + 32256);                        // [2][49][66]    25872 B
    __hip_bfloat16* tsh = (__hip_bfloat16*)(uni + 58128);    // [64][34]       4352 B
    // phase B views (A dead)
    __hip_bfloat16* zsh  = (__hip_bfloat16*)uni;             // [4][16][264]   33792 B
    __hip_bfloat16* ylds = (__hip_bfloat16*)(uni + 33792);   // [64][136]      17408 B

    int b = blockIdx.x & 7, h = blockIdx.x >> 3;   // XCD-aware: batch b -> XCD b
    int tid = threadIdx.x, lane = tid & 63, q = tid >> 6;    // wave q = m-tile
    int l15 = lane & 15, l4 = lane >> 4;
    int m0 = q * 16;

    // ---- staging geometry hoisted: 3920 elems, 16 iters x 256 ----
    auto stage = [&](int g, int buf) {
        const float* xg = x + ((size_t)b * DIM + g * GC) * (Hs * Ws);
        h2v* xb = xp2 + buf * 4032;
#pragma unroll
        for (int hf = 0; hf < 2; ++hf) {
            float v0[8], v1[8];
#pragma unroll
            for (int e = 0; e < 8; ++e) {
                int i = tid + (hf * 8 + e) * 256;
                int ccp = i / 490;
                int rem = i - ccp * 490;
                int r = rem / 70, col = rem - r * 70;
                int hh = h + r - PADn, wc = col - PADn;
                bool ok = (i < 3920) & ((unsigned)hh < (unsigned)Hs) &
                          ((unsigned)wc < (unsigned)Ws);
                int off = ok ? ((ccp * Hs + hh) * Ws + wc) : 0;
                v0[e] = ok ? xg[off] : 0.f;
                v1[e] = ok ? xg[off + 8 * Hs * Ws] : 0.f;
            }
#pragma unroll
            for (int e = 0; e < 8; ++e) {
                int i = tid + (hf * 8 + e) * 256;
                if (i < 3920) {
                    int ccp = i / 490;
                    int rem = i - ccp * 490;
                    int r = rem / 70, col = rem - r * 70;
                    xb[ccp * 504 + r * 72 + col] = pk2h(v0[e], v1[e]);
                }
            }
        }
    };

    // conv2 for group g -> wgt2[buf]; wave q = its m-tile, loops all 4 n-tiles
    auto conv2g = [&](int g, int buf, bf16x8 a_t) {
        f32x4 ac[4];
#pragma unroll
        for (int nt = 0; nt < 4; ++nt) ac[nt] = (f32x4){0.f, 0.f, 0.f, 0.f};
#pragma unroll
        for (int nt = 0; nt < 4; ++nt) {
            bf16x8 bf = *(const bf16x8*)&w2b[(size_t)(g * 49 + nt * 16 + l15) * CMID + l4 * 8];
            ac[nt] = mfma16(a_t, bf, ac[nt]);
        }
        h2v* wb = wgt2 + buf * 3234;
#pragma unroll
        for (int nt = 0; nt < 4; ++nt) {
            int p = nt * 16 + l15;
            if (p < 49) {
                float bias = b2v[g * 49 + p];
#pragma unroll
                for (int r = 0; r < 4; ++r) {
                    _Float16 hf16 = (_Float16)(ac[nt][r] + bias);
                    wb[p * 66 + m0 + l4 * 4 + r] = (h2v){hf16, hf16};
                }
            }
        }
    };

    // ---- conv1 via MFMA (wave q: m-tile q, n-tiles 0..1) ----
    bf16x8 afr[4];
#pragma unroll
    for (int ks = 0; ks < 4; ++ks)
#pragma unroll
        for (int i = 0; i < 8; ++i) {
            int c = ks * 32 + l4 * 8 + i;
            afr[ks][i] = tobf(x[(((size_t)b * DIM + c) * Hs + h) * Ws + m0 + l15]);
        }

    stage(0, 0);

    f32x4 acc1[2];
    acc1[0] = (f32x4){0.f, 0.f, 0.f, 0.f};
    acc1[1] = (f32x4){0.f, 0.f, 0.f, 0.f};
#pragma unroll
    for (int nt = 0; nt < 2; ++nt)
#pragma unroll
        for (int ks = 0; ks < 4; ++ks) {
            bf16x8 bf = *(const bf16x8*)&w1b[(nt * 16 + l15) * DIM + ks * 32 + l4 * 8];
            acc1[nt] = mfma16(afr[ks], bf, acc1[nt]);
        }
#pragma unroll
    for (int nt = 0; nt < 2; ++nt) {
        int o = nt * 16 + l15;
        float sc = bng[o] * rsqrtf(bnv[o] + 1e-5f);
        float sh = bnb[o] - bnm[o] * sc;
        float bv = b1v[o];
#pragma unroll
        for (int r = 0; r < 4; ++r) {
            float v = (acc1[nt][r] + bv) * sc + sh;
            tsh[(m0 + l4 * 4 + r) * 34 + o] = __float2bfloat16(fmaxf(v, 0.f));
        }
    }
    __syncthreads();   // tsh + stage(0) visible

    bf16x8 a_t = *(const bf16x8*)&tsh[(m0 + l15) * 34 + l4 * 8];

    conv2g(0, 0, a_t);
    __syncthreads();   // wgt2[0] visible

    unsigned ypk[16];   // word g*2+hf: channels (g*16+q+8hf lo, g*16+q+4+8hf hi)
    float s = 0.f, ss = 0.f;

#pragma unroll 1
    for (int g = 0; g < Gn; ++g) {
        int buf = g & 1;
        // prefetch next group's inputs concurrently with involution(g)
        if (g < Gn - 1) {
            stage(g + 1, buf ^ 1);
            conv2g(g + 1, buf ^ 1, a_t);
        }

        h2v wv[49];
        const h2v* wb = wgt2 + buf * 3234;
#pragma unroll
        for (int p = 0; p < 49; ++p) wv[p] = wb[p * 66 + lane];

        float a00, a01, a10, a11;
#pragma unroll
        for (int pi = 0; pi < 2; ++pi) {
            int ccp = q + pi * 4;
            const h2v* xrow = xp2 + buf * 4032 + ccp * 504;
            float accx = 0.f, accy = 0.f;
#pragma unroll
            for (int r = 0; r < 7; ++r) {
                h2v hacc = (h2v){(_Float16)0.f, (_Float16)0.f};
#pragma unroll
                for (int j = 0; j < 7; ++j)
                    hacc = wv[r * 7 + j] * xrow[r * 72 + lane + j] + hacc;
                accx += (float)hacc.x;
                accy += (float)hacc.y;
            }
            if (pi == 0) { a00 = accx; a01 = accy; }
            else         { a10 = accx; a11 = accy; }
        }
        // channels: a00=g*16+q, a10=+4, a01=+8, a11=+12
        ypk[g * 2]     = su16(a00) | (su16(a10) << 16);
        ypk[g * 2 + 1] = su16(a01) | (su16(a11) << 16);
        s += (a00 + a10) + (a01 + a11);
        ss = fmaf(a00, a00, fmaf(a10, a10, fmaf(a01, a01, fmaf(a11, a11, ss))));
        __syncthreads();   // next-group staging/wgt2 visible; this buf free
    }

    // ---- LayerNorm ----
    ps[q][lane] = s; pss[q][lane] = ss;
    __syncthreads();
    if (tid < 64) {
        float sa = ps[0][tid] + ps[1][tid] + ps[2][tid] + ps[3][tid];
        float sb = pss[0][tid] + pss[1][tid] + pss[2][tid] + pss[3][tid];
        float mu = sa * (1.f / DIM);
        float var = sb * (1.f / DIM) - mu * mu;
        mu_s[tid] = mu;
        rs_s[tid] = rsqrtf(var + 1e-6f);
    }
    __syncthreads();
    {
        float mu = mu_s[lane], rs = rs_s[lane];
        unsigned wds[16];
#pragma unroll
        for (int g = 0; g < 8; ++g)
#pragma unroll
            for (int hf = 0; hf < 2; ++hf) {
                unsigned wk = ypk[g * 2 + hf];
                float lo = __uint_as_float(wk << 16);
                float hi = __uint_as_float(wk & 0xffff0000u);
                int c0 = g * 16 + q + hf * 8, c1 = c0 + 4;
                lo = (lo - mu) * rs * lng[c0] + lnb[c0];
                hi = (hi - mu) * rs * lng[c1] + lnb[c1];
                // permuted j: q*32 + g*4 + (hf?2:0) pairs (m, m+1) = (lo@4m, hi@4m+4)
                wds[g * 2 + hf] = su16(lo) | (su16(hi) << 16);
            }
        // j-order within thread: g0:{m0,m1},{m2,m3}, g1:... => words [g*2], [g*2+1]
        __hip_bfloat16* dst = ylds + lane * 136 + q * 32;
#pragma unroll
        for (int c4 = 0; c4 < 4; ++c4) {
            uint4 vv;
            vv.x = wds[c4 * 4 + 0];   // g=2c4,   m01
            vv.y = wds[c4 * 4 + 1];   // g=2c4,   m23
            vv.z = wds[c4 * 4 + 2];   // g=2c4+1, m01
            vv.w = wds[c4 * 4 + 3];   // g=2c4+1, m23
            *(uint4*)&dst[c4 * 8] = vv;
        }
    }
    __syncthreads();   // ylds ready (phase A LDS dead)

    // ---- MLP GEMM1: wave q = m-tile q, all 16 n-tiles ----
    bf16x8 ay[4];
#pragma unroll
    for (int ks = 0; ks < 4; ++ks)
        ay[ks] = *(const bf16x8*)&ylds[(m0 + l15) * 136 + ks * 32 + l4 * 8];

    __hip_bfloat16* zw = zsh + q * 16 * 264;   // wave-private slice
    {
        f32x4 zac[16];
#pragma unroll
        for (int n = 0; n < 16; ++n) zac[n] = (f32x4){0.f, 0.f, 0.f, 0.f};
#pragma unroll
        for (int ks = 0; ks < 4; ++ks)
#pragma unroll
            for (int n = 0; n < 16; ++n) {
                bf16x8 bf = *(const bf16x8*)&mw1b[(n * 16 + l15) * DIM + ks * 32 + l4 * 8];
                zac[n] = mfma16(ay[ks], bf, zac[n]);
            }
#pragma unroll
        for (int n = 0; n < 16; ++n) {
            float bv = mb1[n * 16 + l15];
#pragma unroll
            for (int r = 0; r < 4; ++r) {
                float v = gelu_t(zac[n][r] + bv);
                zw[(l4 * 4 + r) * 264 + n * 16 + l15] = __float2bfloat16(v);
            }
        }
    }
    // no barrier: zw is wave-private

    // ---- MLP GEMM2: 8 n-tiles ----
    bf16x8 az[8];
#pragma unroll
    for (int ks = 0; ks < 8; ++ks)
        az[ks] = *(const bf16x8*)&zw[l15 * 264 + ks * 32 + l4 * 8];

    f32x4 oac[8];
#pragma unroll
    for (int n = 0; n < 8; ++n) oac[n] = (f32x4){0.f, 0.f, 0.f, 0.f};
#pragma unroll
    for (int ks = 0; ks < 8; ++ks)
#pragma unroll
        for (int n = 0; n < 8; ++n) {
            bf16x8 bf = *(const bf16x8*)&mw2b[(n * 16 + l15) * 256 + ks * 32 + l4 * 8];
            oac[n] = mfma16(az[ks], bf, oac[n]);
        }

    float4 xr[8];
#pragma unroll
    for (int n = 0; n < 8; ++n) {
        int c = n * 16 + l15;
        xr[n] = *(const float4*)&x[(((size_t)b * DIM + c) * Hs + h) * Ws + m0 + l4 * 4];
    }
#pragma unroll
    for (int n = 0; n < 8; ++n) {
        int c = n * 16 + l15;
        float bv = mb2[c];
        size_t gi = (((size_t)b * DIM + c) * Hs + h) * Ws + m0 + l4 * 4;
        float4 o;
        o.x = oac[n][0] + bv + xr[n].x;
        o.y = oac[n][1] + bv + xr[n].y;
        o.z = oac[n][2] + bv + xr[n].z;
        o.w = oac[n][3] + bv + xr[n].w;
        *(float4*)&out[gi] = o;
    }
}

extern "C" void kernel_launch(void* const* d_in, const int* in_sizes, int n_in,
                              void* d_out, int out_size, void* d_ws, size_t ws_size,
                              hipStream_t stream) {
    const float* x       = (const float*)d_in[0];
    const float* conv1_w = (const float*)d_in[1];
    const float* conv1_b = (const float*)d_in[2];
    const float* bn_g    = (const float*)d_in[3];
    const float* bn_b    = (const float*)d_in[4];
    const float* bn_mean = (const float*)d_in[5];
    const float* bn_var  = (const float*)d_in[6];
    const float* conv2_w = (const float*)d_in[7];
    const float* conv2_b = (const float*)d_in[8];
    const float* ln_g    = (const float*)d_in[9];
    const float* ln_b    = (const float*)d_in[10];
    const float* pw1_w   = (const float*)d_in[11];
    const float* pw1_b   = (const float*)d_in[12];
    const float* pw2_w   = (const float*)d_in[13];
    const float* pw2_b   = (const float*)d_in[14];
    float* out = (float*)d_out;

    char* ws = (char*)d_ws;
    __hip_bfloat16* w1b  = (__hip_bfloat16*)ws;              // 8 KB
    __hip_bfloat16* w2b  = (__hip_bfloat16*)(ws + 8192);     // 26 KB
    __hip_bfloat16* mw1b = (__hip_bfloat16*)(ws + 34816);    // 64 KB (K-permuted)
    __hip_bfloat16* mw2b = (__hip_bfloat16*)(ws + 100352);   // 64 KB

    hipLaunchKernelGGL(k0_cvt, dim3(128), dim3(256), 0, stream,
                       conv1_w, conv2_w, pw1_w, pw2_w, w1b, w2b, mw1b, mw2b);
    hipLaunchKernelGGL(k_all, dim3(Bn * Hs), dim3(256), 0, stream,
                       x, w1b, conv1_b, bn_g, bn_b, bn_mean, bn_var,
                       w2b, conv2_b, ln_g, ln_b,
                       mw1b, pw1_b, mw2b, pw2_b, out);
}

// Round 13
// 72.143 us; speedup vs baseline: 1.3574x; 1.3574x over previous
//
#include <hip/hip_runtime.h>
#include <hip/hip_bf16.h>
#include <math.h>

#define Bn   8
#define DIM  128
#define Hs   64
#define Ws   64
#define PADn 3
#define GC   16
#define Gn   8
#define CMID 32    // DIM/RED
#define NW   392   // K*K*G
#define NWP  416   // w2b padded rows

typedef __bf16 bf16x8 __attribute__((ext_vector_type(8)));
typedef float  f32x4  __attribute__((ext_vector_type(4)));
typedef _Float16 h2v  __attribute__((ext_vector_type(2)));
typedef __fp16   fp16x2 __attribute__((ext_vector_type(2)));

__device__ __forceinline__ f32x4 mfma16(bf16x8 a, bf16x8 b, f32x4 c) {
    return __builtin_amdgcn_mfma_f32_16x16x32_bf16(a, b, c, 0, 0, 0);
}

__device__ __forceinline__ __bf16 tobf(float v) {
    __hip_bfloat16 h = __float2bfloat16(v);
    return *reinterpret_cast<__bf16*>(&h);
}

__device__ __forceinline__ unsigned su16(float f) {
    __hip_bfloat16 h = __float2bfloat16(f);
    return (unsigned)*reinterpret_cast<unsigned short*>(&h);
}

__device__ __forceinline__ unsigned pk2u(float a, float b) {
    fp16x2 p = __builtin_amdgcn_cvt_pkrtz(a, b);
    return __builtin_bit_cast(unsigned, p);
}

// tanh-form gelu
__device__ __forceinline__ float gelu_t(float v) {
    float u = 0.7978845608f * v * fmaf(0.044715f, v * v, 1.0f);
    float t = __builtin_amdgcn_exp2f(fminf(u, 30.f) * 2.885390082f);
    return v * t * __builtin_amdgcn_rcpf(t + 1.0f);
}

// ---------------- K0: weights -> bf16 (+pw1 K-perm); x -> packed f16 pairs ----------------
// xpair[(b*8+g)*8+ccp][pix] = pk_f16(x[b][g*16+ccp][pix], x[b][g*16+ccp+8][pix])
__global__ __launch_bounds__(256) void k0_cvt(const float* __restrict__ w1,
        const float* __restrict__ w2,
        const float* __restrict__ pw1, const float* __restrict__ pw2,
        const float* __restrict__ x,
        __hip_bfloat16* __restrict__ w1b, __hip_bfloat16* __restrict__ w2b,
        __hip_bfloat16* __restrict__ mw1b, __hip_bfloat16* __restrict__ mw2b,
        unsigned* __restrict__ xpair) {
    int T = blockIdx.x * 256 + threadIdx.x;   // 524288 threads
    if (T < 32768) {
        int i = T;
        if (i < CMID * DIM) w1b[i] = __float2bfloat16(w1[i]);
        if (i < NWP * CMID)
            w2b[i] = (i < NW * CMID) ? __float2bfloat16(w2[i]) : __float2bfloat16(0.f);
        {
            int f = i >> 7, j = i & 127;
            int qq = j >> 5, gg = (j >> 2) & 7, mm = j & 3;
            mw1b[i] = __float2bfloat16(pw1[f * 128 + gg * 16 + qq + 4 * mm]);
        }
        mw2b[i] = __float2bfloat16(pw2[i]);
    }
    // x pairs: c8 = (b,g,ccp) 0..511, each thread one float4-group of pixels
    int c8 = T >> 10;
    int p4 = (T & 1023) * 4;
    int bb = c8 >> 6, gg = (c8 >> 3) & 7, cc = c8 & 7;
    size_t src = ((size_t)(bb * DIM + gg * GC + cc)) * 4096 + p4;
    float4 lo = *(const float4*)&x[src];
    float4 hi = *(const float4*)&x[src + 8 * 4096];
    uint4 o;
    o.x = pk2u(lo.x, hi.x);
    o.y = pk2u(lo.y, hi.y);
    o.z = pk2u(lo.z, hi.z);
    o.w = pk2u(lo.w, hi.w);
    *(uint4*)&xpair[(size_t)c8 * 4096 + p4] = o;
}

// ---- K_ALL: 256 threads / 4 waves, 36.3KB LDS -> 4 blocks/CU ----
__global__ __launch_bounds__(256) void k_all(const float* __restrict__ x,
        const unsigned* __restrict__ xpair,
        const __hip_bfloat16* __restrict__ w1b, const float* __restrict__ b1v,
        const float* __restrict__ bng, const float* __restrict__ bnb,
        const float* __restrict__ bnm, const float* __restrict__ bnv,
        const __hip_bfloat16* __restrict__ w2b, const float* __restrict__ b2v,
        const float* __restrict__ lng, const float* __restrict__ lnb,
        const __hip_bfloat16* __restrict__ mw1b, const float* __restrict__ mb1,
        const __hip_bfloat16* __restrict__ mw2b, const float* __restrict__ mb2,
        float* __restrict__ out) {
    __shared__ __align__(16) char uni[33792];
    __shared__ float ps[4][64], pss[4][64], mu_s[64], rs_s[64];   // 2.5 KB
    // phase A views (total 33424 B)
    h2v* xp    = (h2v*)uni;                                  // [8][7][72]   16128 B
    h2v* wgt2  = (h2v*)(uni + 16128);                        // [49][66]     12936 B
    __hip_bfloat16* tsh = (__hip_bfloat16*)(uni + 29072);    // [64][34]     4352 B
    // phase B views (A dead)
    __hip_bfloat16* ylds = (__hip_bfloat16*)uni;             // [64][136]    17408 B
    __hip_bfloat16* zsh  = (__hip_bfloat16*)uni;             // [4][16][264] 33792 B (after ay hoist)

    int b = blockIdx.x & 7, h = blockIdx.x >> 3;   // XCD-aware: batch b -> XCD b
    int tid = threadIdx.x, lane = tid & 63, q = tid >> 6;
    int l15 = lane & 15, l4 = lane >> 4;
    int m0 = q * 16;

    // ---- stage geometry: computed ONCE (g-invariant). goff<0 => load 0 ----
    int goff[16];
    unsigned ldsoPk[8];
#pragma unroll
    for (int e = 0; e < 16; ++e) {
        int i = tid + e * 256;
        int ccp = i / 490;
        int rem = i - ccp * 490;
        int r = rem / 70, col = rem - r * 70;
        int hh = h + r - PADn, wc = col - PADn;
        bool ok = (i < 3920) & ((unsigned)hh < (unsigned)Hs) & ((unsigned)wc < (unsigned)Ws);
        goff[e] = ok ? (ccp * 4096 + hh * 64 + wc) : -1;
        unsigned lo16 = (unsigned)(ccp * 504 + r * 72 + col);
        if ((e & 1) == 0) ldsoPk[e >> 1] = lo16;
        else              ldsoPk[e >> 1] |= lo16 << 16;
    }

    auto stage = [&](int g) {
        const unsigned* xg = xpair + (size_t)(b * 64 + g * 8) * 4096;
#pragma unroll
        for (int hf = 0; hf < 2; ++hf) {
            unsigned v[8];
#pragma unroll
            for (int e8 = 0; e8 < 8; ++e8) {
                int go = goff[hf * 8 + e8];
                v[e8] = (go >= 0) ? xg[go] : 0u;
            }
#pragma unroll
            for (int e8 = 0; e8 < 8; ++e8) {
                int e = hf * 8 + e8;
                if (e < 15 || tid < 80) {   // i < 3920
                    unsigned ldso = (ldsoPk[e >> 1] >> ((e & 1) * 16)) & 0xFFFFu;
                    *(unsigned*)&xp[ldso] = v[e8];
                }
            }
        }
    };

    // ---- conv1 via MFMA (wave q: m-tile q, 2 n-tiles) ----
    bf16x8 afr[4];
#pragma unroll
    for (int ks = 0; ks < 4; ++ks)
#pragma unroll
        for (int i = 0; i < 8; ++i) {
            int c = ks * 32 + l4 * 8 + i;
            afr[ks][i] = tobf(x[(((size_t)b * DIM + c) * Hs + h) * Ws + m0 + l15]);
        }
    f32x4 acc1[2];
    acc1[0] = (f32x4){0.f, 0.f, 0.f, 0.f};
    acc1[1] = (f32x4){0.f, 0.f, 0.f, 0.f};
#pragma unroll
    for (int nt = 0; nt < 2; ++nt)
#pragma unroll
        for (int ks = 0; ks < 4; ++ks) {
            bf16x8 bf = *(const bf16x8*)&w1b[(nt * 16 + l15) * DIM + ks * 32 + l4 * 8];
            acc1[nt] = mfma16(afr[ks], bf, acc1[nt]);
        }
#pragma unroll
    for (int nt = 0; nt < 2; ++nt) {
        int o = nt * 16 + l15;
        float sc = bng[o] * rsqrtf(bnv[o] + 1e-5f);
        float sh = bnb[o] - bnm[o] * sc;
        float bv = b1v[o];
#pragma unroll
        for (int r = 0; r < 4; ++r) {
            float v = (acc1[nt][r] + bv) * sc + sh;
            tsh[(m0 + l4 * 4 + r) * 34 + o] = __float2bfloat16(fmaxf(v, 0.f));
        }
    }
    __syncthreads();   // tsh visible

    bf16x8 a_t = *(const bf16x8*)&tsh[(m0 + l15) * 34 + l4 * 8];

    unsigned ypk[16];   // word g*2+hf: channels (g*16+q+8hf lo, +4 hi)
    float s = 0.f, ss = 0.f;

#pragma unroll 1
    for (int g = 0; g < Gn; ++g) {
        stage(g);
        // conv2(g): wave q = m-tile q, all 4 n-tiles
        {
            f32x4 ac[4];
#pragma unroll
            for (int nt = 0; nt < 4; ++nt) ac[nt] = (f32x4){0.f, 0.f, 0.f, 0.f};
#pragma unroll
            for (int nt = 0; nt < 4; ++nt) {
                bf16x8 bf = *(const bf16x8*)&w2b[(size_t)(g * 49 + nt * 16 + l15) * CMID + l4 * 8];
                ac[nt] = mfma16(a_t, bf, ac[nt]);
            }
#pragma unroll
            for (int nt = 0; nt < 4; ++nt) {
                int p = nt * 16 + l15;
                if (p < 49) {
                    float bias = b2v[g * 49 + p];
#pragma unroll
                    for (int r = 0; r < 4; ++r) {
                        _Float16 hf16 = (_Float16)(ac[nt][r] + bias);
                        wgt2[p * 66 + m0 + l4 * 4 + r] = (h2v){hf16, hf16};
                    }
                }
            }
        }
        __syncthreads();   // xp + wgt2 for group g visible

        // involution: row-chunked wv to cap VGPR (28 then 21 taps)
        float a00 = 0.f, a01 = 0.f, a10 = 0.f, a11 = 0.f;
        {
            h2v wv[28];
#pragma unroll
            for (int p = 0; p < 28; ++p) wv[p] = wgt2[p * 66 + lane];
#pragma unroll
            for (int pi = 0; pi < 2; ++pi) {
                const h2v* xrow = xp + (q + pi * 4) * 504;
                float accx = 0.f, accy = 0.f;
#pragma unroll
                for (int r = 0; r < 4; ++r) {
                    h2v hacc = (h2v){(_Float16)0.f, (_Float16)0.f};
#pragma unroll
                    for (int j = 0; j < 7; ++j)
                        hacc = wv[r * 7 + j] * xrow[r * 72 + lane + j] + hacc;
                    accx += (float)hacc.x;
                    accy += (float)hacc.y;
                }
                if (pi == 0) { a00 = accx; a01 = accy; }
                else         { a10 = accx; a11 = accy; }
            }
        }
        {
            h2v wv[21];
#pragma unroll
            for (int p = 0; p < 21; ++p) wv[p] = wgt2[(28 + p) * 66 + lane];
#pragma unroll
            for (int pi = 0; pi < 2; ++pi) {
                const h2v* xrow = xp + (q + pi * 4) * 504;
                float accx = 0.f, accy = 0.f;
#pragma unroll
                for (int r = 0; r < 3; ++r) {
                    h2v hacc = (h2v){(_Float16)0.f, (_Float16)0.f};
#pragma unroll
                    for (int j = 0; j < 7; ++j)
                        hacc = wv[r * 7 + j] * xrow[(r + 4) * 72 + lane + j] + hacc;
                    accx += (float)hacc.x;
                    accy += (float)hacc.y;
                }
                if (pi == 0) { a00 += accx; a01 += accy; }
                else         { a10 += accx; a11 += accy; }
            }
        }
        // channels: a00=g*16+q, a10=+4, a01=+8, a11=+12
        ypk[g * 2]     = su16(a00) | (su16(a10) << 16);
        ypk[g * 2 + 1] = su16(a01) | (su16(a11) << 16);
        s += (a00 + a10) + (a01 + a11);
        ss = fmaf(a00, a00, fmaf(a10, a10, fmaf(a01, a01, fmaf(a11, a11, ss))));
        __syncthreads();   // involution reads done; xp/wgt2 free for next g
    }

    // ---- LayerNorm ----
    ps[q][lane] = s; pss[q][lane] = ss;
    __syncthreads();
    if (tid < 64) {
        float sa = ps[0][tid] + ps[1][tid] + ps[2][tid] + ps[3][tid];
        float sb = pss[0][tid] + pss[1][tid] + pss[2][tid] + pss[3][tid];
        float mu = sa * (1.f / DIM);
        float var = sb * (1.f / DIM) - mu * mu;
        mu_s[tid] = mu;
        rs_s[tid] = rsqrtf(var + 1e-6f);
    }
    __syncthreads();
    {
        float mu = mu_s[lane], rs = rs_s[lane];
        unsigned wds[16];
#pragma unroll
        for (int g = 0; g < 8; ++g)
#pragma unroll
            for (int hf = 0; hf < 2; ++hf) {
                unsigned wk = ypk[g * 2 + hf];
                float lo = __uint_as_float(wk << 16);
                float hi = __uint_as_float(wk & 0xffff0000u);
                int c0 = g * 16 + q + hf * 8, c1 = c0 + 4;
                lo = (lo - mu) * rs * lng[c0] + lnb[c0];
                hi = (hi - mu) * rs * lng[c1] + lnb[c1];
                wds[g * 2 + hf] = su16(lo) | (su16(hi) << 16);
            }
        // permuted channel layout (matches mw1b K-perm): thread writes its 32 j's
        __hip_bfloat16* dst = ylds + lane * 136 + q * 32;
#pragma unroll
        for (int c4 = 0; c4 < 4; ++c4) {
            uint4 vv;
            vv.x = wds[c4 * 4 + 0];
            vv.y = wds[c4 * 4 + 1];
            vv.z = wds[c4 * 4 + 2];
            vv.w = wds[c4 * 4 + 3];
            *(uint4*)&dst[c4 * 8] = vv;
        }
    }
    __syncthreads();   // ylds ready

    // ---- hoist A-frags for GEMM1, then free ylds region for zsh ----
    bf16x8 ay[4];
#pragma unroll
    for (int ks = 0; ks < 4; ++ks)
        ay[ks] = *(const bf16x8*)&ylds[(m0 + l15) * 136 + ks * 32 + l4 * 8];
    __syncthreads();   // all ay reads done; zsh may overwrite

    __hip_bfloat16* zw = zsh + q * 16 * 264;   // wave-private slice
#pragma unroll
    for (int half = 0; half < 2; ++half) {
        f32x4 zac[8];
#pragma unroll
        for (int n = 0; n < 8; ++n) zac[n] = (f32x4){0.f, 0.f, 0.f, 0.f};
#pragma unroll
        for (int ks = 0; ks < 4; ++ks)
#pragma unroll
            for (int n = 0; n < 8; ++n) {
                int nt = half * 8 + n;
                bf16x8 bf = *(const bf16x8*)&mw1b[(nt * 16 + l15) * DIM + ks * 32 + l4 * 8];
                zac[n] = mfma16(ay[ks], bf, zac[n]);
            }
#pragma unroll
        for (int n = 0; n < 8; ++n) {
            int nt = half * 8 + n;
            float bv = mb1[nt * 16 + l15];
#pragma unroll
            for (int r = 0; r < 4; ++r) {
                float v = gelu_t(zac[n][r] + bv);
                zw[(l4 * 4 + r) * 264 + nt * 16 + l15] = __float2bfloat16(v);
            }
        }
    }
    // no barrier: zw wave-private, same-wave ds ordering

    bf16x8 az[8];
#pragma unroll
    for (int ks = 0; ks < 8; ++ks)
        az[ks] = *(const bf16x8*)&zw[l15 * 264 + ks * 32 + l4 * 8];

    f32x4 oac[8];
#pragma unroll
    for (int n = 0; n < 8; ++n) oac[n] = (f32x4){0.f, 0.f, 0.f, 0.f};
#pragma unroll
    for (int ks = 0; ks < 8; ++ks)
#pragma unroll
        for (int n = 0; n < 8; ++n) {
            bf16x8 bf = *(const bf16x8*)&mw2b[(n * 16 + l15) * 256 + ks * 32 + l4 * 8];
            oac[n] = mfma16(az[ks], bf, oac[n]);
        }

    float4 xr[8];
#pragma unroll
    for (int n = 0; n < 8; ++n) {
        int c = n * 16 + l15;
        xr[n] = *(const float4*)&x[(((size_t)b * DIM + c) * Hs + h) * Ws + m0 + l4 * 4];
    }
#pragma unroll
    for (int n = 0; n < 8; ++n) {
        int c = n * 16 + l15;
        float bv = mb2[c];
        size_t gi = (((size_t)b * DIM + c) * Hs + h) * Ws + m0 + l4 * 4;
        float4 o;
        o.x = oac[n][0] + bv + xr[n].x;
        o.y = oac[n][1] + bv + xr[n].y;
        o.z = oac[n][2] + bv + xr[n].z;
        o.w = oac[n][3] + bv + xr[n].w;
        *(float4*)&out[gi] = o;
    }
}

extern "C" void kernel_launch(void* const* d_in, const int* in_sizes, int n_in,
                              void* d_out, int out_size, void* d_ws, size_t ws_size,
                              hipStream_t stream) {
    const float* x       = (const float*)d_in[0];
    const float* conv1_w = (const float*)d_in[1];
    const float* conv1_b = (const float*)d_in[2];
    const float* bn_g    = (const float*)d_in[3];
    const float* bn_b    = (const float*)d_in[4];
    const float* bn_mean = (const float*)d_in[5];
    const float* bn_var  = (const float*)d_in[6];
    const float* conv2_w = (const float*)d_in[7];
    const float* conv2_b = (const float*)d_in[8];
    const float* ln_g    = (const float*)d_in[9];
    const float* ln_b    = (const float*)d_in[10];
    const float* pw1_w   = (const float*)d_in[11];
    const float* pw1_b   = (const float*)d_in[12];
    const float* pw2_w   = (const float*)d_in[13];
    const float* pw2_b   = (const float*)d_in[14];
    float* out = (float*)d_out;

    char* ws = (char*)d_ws;
    __hip_bfloat16* w1b  = (__hip_bfloat16*)ws;                   // 8 KB
    __hip_bfloat16* w2b  = (__hip_bfloat16*)(ws + 8192);          // 26 KB
    __hip_bfloat16* mw1b = (__hip_bfloat16*)(ws + 34816);         // 64 KB (K-perm)
    __hip_bfloat16* mw2b = (__hip_bfloat16*)(ws + 100352);        // 64 KB
    unsigned* xpair      = (unsigned*)(ws + (1 << 20));           // 8.4 MB

    hipLaunchKernelGGL(k0_cvt, dim3(2048), dim3(256), 0, stream,
                       conv1_w, conv2_w, pw1_w, pw2_w, x,
                       w1b, w2b, mw1b, mw2b, xpair);
    hipLaunchKernelGGL(k_all, dim3(Bn * Hs), dim3(256), 0, stream,
                       x, xpair, w1b, conv1_b, bn_g, bn_b, bn_mean, bn_var,
                       w2b, conv2_b, ln_g, ln_b,
                       mw1b, pw1_b, mw2b, pw2_b, out);
}

// Round 14
// 70.599 us; speedup vs baseline: 1.3871x; 1.0219x over previous
//
#include <hip/hip_runtime.h>
#include <hip/hip_bf16.h>
#include <math.h>

#define Bn   8
#define DIM  128
#define Hs   64
#define Ws   64
#define PADn 3
#define GC   16
#define Gn   8
#define CMID 32    // DIM/RED
#define NW   392   // K*K*G
#define NWP  416   // w2b padded rows

typedef __bf16 bf16x8 __attribute__((ext_vector_type(8)));
typedef float  f32x4  __attribute__((ext_vector_type(4)));
typedef _Float16 h2v  __attribute__((ext_vector_type(2)));
typedef __fp16   fp16x2 __attribute__((ext_vector_type(2)));

__device__ __forceinline__ f32x4 mfma16(bf16x8 a, bf16x8 b, f32x4 c) {
    return __builtin_amdgcn_mfma_f32_16x16x32_bf16(a, b, c, 0, 0, 0);
}

__device__ __forceinline__ __bf16 tobf(float v) {
    __hip_bfloat16 h = __float2bfloat16(v);
    return *reinterpret_cast<__bf16*>(&h);
}

__device__ __forceinline__ unsigned su16(float f) {
    __hip_bfloat16 h = __float2bfloat16(f);
    return (unsigned)*reinterpret_cast<unsigned short*>(&h);
}

__device__ __forceinline__ unsigned pk2u(float a, float b) {
    fp16x2 p = __builtin_amdgcn_cvt_pkrtz(a, b);
    return __builtin_bit_cast(unsigned, p);
}

// tanh-form gelu
__device__ __forceinline__ float gelu_t(float v) {
    float u = 0.7978845608f * v * fmaf(0.044715f, v * v, 1.0f);
    float t = __builtin_amdgcn_exp2f(fminf(u, 30.f) * 2.885390082f);
    return v * t * __builtin_amdgcn_rcpf(t + 1.0f);
}

// ---------------- K0: weights -> bf16 (+pw1 K-perm for 1-wave layout); x -> f16 pairs ----------------
// Thread channel ownership in k_all: c(j) = g*16 + t4*2 + pi + 8*sel,
// with t4=j>>5, k=j&31, g=k>>2, pi=(k>>1)&1, sel=k&1.
__global__ __launch_bounds__(256) void k0_cvt(const float* __restrict__ w1,
        const float* __restrict__ w2,
        const float* __restrict__ pw1, const float* __restrict__ pw2,
        const float* __restrict__ x,
        __hip_bfloat16* __restrict__ w1b, __hip_bfloat16* __restrict__ w2b,
        __hip_bfloat16* __restrict__ mw1b, __hip_bfloat16* __restrict__ mw2b,
        unsigned* __restrict__ xpair) {
    int T = blockIdx.x * 256 + threadIdx.x;   // 524288 threads
    if (T < 32768) {
        int i = T;
        if (i < CMID * DIM) w1b[i] = __float2bfloat16(w1[i]);
        if (i < NWP * CMID)
            w2b[i] = (i < NW * CMID) ? __float2bfloat16(w2[i]) : __float2bfloat16(0.f);
        {
            int f = i >> 7, j = i & 127;
            int t4 = j >> 5, k = j & 31;
            int g = k >> 2, pi = (k >> 1) & 1, sel = k & 1;
            mw1b[i] = __float2bfloat16(pw1[f * 128 + g * 16 + t4 * 2 + pi + 8 * sel]);
        }
        mw2b[i] = __float2bfloat16(pw2[i]);
    }
    // x pairs: c8 = (b,g,ccp) 0..511, each thread one float4-group of pixels
    int c8 = T >> 10;
    int p4 = (T & 1023) * 4;
    int bb = c8 >> 6, gg = (c8 >> 3) & 7, cc = c8 & 7;
    size_t src = ((size_t)(bb * DIM + gg * GC + cc)) * 4096 + p4;
    float4 lo = *(const float4*)&x[src];
    float4 hi = *(const float4*)&x[src + 8 * 4096];
    uint4 o;
    o.x = pk2u(lo.x, hi.x);
    o.y = pk2u(lo.y, hi.y);
    o.z = pk2u(lo.z, hi.z);
    o.w = pk2u(lo.w, hi.w);
    *(uint4*)&xpair[(size_t)c8 * 4096 + p4] = o;
}

// ---- K_ALL: ONE WAVE per block, 16-pixel tile, ZERO barriers ----
__global__ __launch_bounds__(64) void k_all(const float* __restrict__ x,
        const unsigned* __restrict__ xpair,
        const __hip_bfloat16* __restrict__ w1b, const float* __restrict__ b1v,
        const float* __restrict__ bng, const float* __restrict__ bnb,
        const float* __restrict__ bnm, const float* __restrict__ bnv,
        const __hip_bfloat16* __restrict__ w2b, const float* __restrict__ b2v,
        const float* __restrict__ lng, const float* __restrict__ lnb,
        const __hip_bfloat16* __restrict__ mw1b, const float* __restrict__ mb1,
        const __hip_bfloat16* __restrict__ mw2b, const float* __restrict__ mb2,
        float* __restrict__ out) {
    __shared__ __align__(16) char uni[15368];
    // phase A
    h2v* xp    = (h2v*)uni;                                  // [2][8][7][24]  10752 B
    h2v* wgt2  = (h2v*)(uni + 10752);                        // [49][18]       3528 B
    __hip_bfloat16* tsh = (__hip_bfloat16*)(uni + 14280);    // [16][34]       1088 B
    // phase B (A dead; ylds/zsh disjoint)
    __hip_bfloat16* ylds = (__hip_bfloat16*)uni;             // [16][136]      4352 B
    __hip_bfloat16* zsh  = (__hip_bfloat16*)(uni + 4352);    // [16][264]      8448 B

    int bid = blockIdx.x;
    int b = bid & 7;                    // XCD-aware: batch b -> XCD b
    int rest = bid >> 3;                // 0..255
    int h = rest >> 2, wq = rest & 3;
    int w0 = wq * 16;
    int lane = threadIdx.x;
    int l15 = lane & 15, l4 = lane >> 4;
    int px = l15, t4 = l4;              // involution roles

    // ---- stage geometry (g-invariant): 8ccp x 7r x 22col = 1232 elems, 20 iters x 64 ----
    int goff[20];
    unsigned short ldso[20];
#pragma unroll
    for (int e = 0; e < 20; ++e) {
        int i = lane + e * 64;
        int ccp = i / 154;
        int rem = i - ccp * 154;
        int r = rem / 22, col = rem - r * 22;
        int hh = h + r - PADn, wc = w0 + col - PADn;
        bool ok = (i < 1232) & ((unsigned)hh < (unsigned)Hs) & ((unsigned)wc < (unsigned)Ws);
        goff[e] = ok ? (ccp * 4096 + hh * 64 + wc) : -1;
        ldso[e] = (unsigned short)(ccp * 168 + r * 24 + col);
    }

    auto stage = [&](int g, int buf) {
        const unsigned* xg = xpair + (size_t)(b * 64 + g * 8) * 4096;
        unsigned v[20];
#pragma unroll
        for (int e = 0; e < 20; ++e)
            v[e] = (goff[e] >= 0) ? xg[goff[e]] : 0u;
#pragma unroll
        for (int e = 0; e < 20; ++e)
            if (e < 19 || lane < 16)    // i < 1232
                *(unsigned*)&xp[buf * 1344 + ldso[e]] = v[e];
    };

    // ---- conv1 via MFMA (one m-tile of 16 pixels, 2 n-tiles) ----
    bf16x8 afr[4];
#pragma unroll
    for (int ks = 0; ks < 4; ++ks)
#pragma unroll
        for (int i = 0; i < 8; ++i) {
            int c = ks * 32 + l4 * 8 + i;
            afr[ks][i] = tobf(x[(((size_t)b * DIM + c) * Hs + h) * Ws + w0 + l15]);
        }

    stage(0, 0);

    f32x4 acc1[2];
    acc1[0] = (f32x4){0.f, 0.f, 0.f, 0.f};
    acc1[1] = (f32x4){0.f, 0.f, 0.f, 0.f};
#pragma unroll
    for (int nt = 0; nt < 2; ++nt)
#pragma unroll
        for (int ks = 0; ks < 4; ++ks) {
            bf16x8 bf = *(const bf16x8*)&w1b[(nt * 16 + l15) * DIM + ks * 32 + l4 * 8];
            acc1[nt] = mfma16(afr[ks], bf, acc1[nt]);
        }
#pragma unroll
    for (int nt = 0; nt < 2; ++nt) {
        int o = nt * 16 + l15;
        float sc = bng[o] * rsqrtf(bnv[o] + 1e-5f);
        float sh = bnb[o] - bnm[o] * sc;
        float bv = b1v[o];
#pragma unroll
        for (int r = 0; r < 4; ++r) {
            float v = (acc1[nt][r] + bv) * sc + sh;
            tsh[(l4 * 4 + r) * 34 + o] = __float2bfloat16(fmaxf(v, 0.f));
        }
    }
    // same wave: tsh in-order visible
    bf16x8 a_t = *(const bf16x8*)&tsh[l15 * 34 + l4 * 8];

    unsigned ypk[16];   // word g*2+pi: (lo: c=g*16+t4*2+pi, hi: +8)
    float s = 0.f, ss = 0.f;

#pragma unroll 1
    for (int g = 0; g < Gn; ++g) {
        int buf = g & 1;
        if (g == 0) ;                       // stage(0) already done
        else stage(g, buf);

        // conv2(g): 4 n-tiles
        {
            f32x4 ac[4];
#pragma unroll
            for (int nt = 0; nt < 4; ++nt) ac[nt] = (f32x4){0.f, 0.f, 0.f, 0.f};
#pragma unroll
            for (int nt = 0; nt < 4; ++nt) {
                bf16x8 bf = *(const bf16x8*)&w2b[(size_t)(g * 49 + nt * 16 + l15) * CMID + l4 * 8];
                ac[nt] = mfma16(a_t, bf, ac[nt]);
            }
#pragma unroll
            for (int nt = 0; nt < 4; ++nt) {
                int p = nt * 16 + l15;
                if (p < 49) {
                    float bias = b2v[g * 49 + p];
#pragma unroll
                    for (int r = 0; r < 4; ++r) {
                        _Float16 hf16 = (_Float16)(ac[nt][r] + bias);
                        wgt2[p * 18 + l4 * 4 + r] = (h2v){hf16, hf16};
                    }
                }
            }
        }
        // same wave: wgt2 + xp[buf] in-order visible, no barrier

        h2v wv[49];
#pragma unroll
        for (int p = 0; p < 49; ++p) wv[p] = wgt2[p * 18 + px];

#pragma unroll
        for (int pi = 0; pi < 2; ++pi) {
            int ccp = t4 * 2 + pi;
            const h2v* xrow = xp + buf * 1344 + ccp * 168;
            float accx = 0.f, accy = 0.f;
#pragma unroll
            for (int r = 0; r < 7; ++r) {
                h2v hacc = (h2v){(_Float16)0.f, (_Float16)0.f};
#pragma unroll
                for (int j = 0; j < 7; ++j)
                    hacc = wv[r * 7 + j] * xrow[r * 24 + px + j] + hacc;
                accx += (float)hacc.x;
                accy += (float)hacc.y;
            }
            ypk[g * 2 + pi] = su16(accx) | (su16(accy) << 16);
            s += accx + accy;
            ss = fmaf(accx, accx, fmaf(accy, accy, ss));
        }
    }

    // ---- LayerNorm: quad reduce over lanes {px, px+16, px+32, px+48} ----
    s += __shfl_xor(s, 16);  s += __shfl_xor(s, 32);
    ss += __shfl_xor(ss, 16); ss += __shfl_xor(ss, 32);
    float mu = s * (1.f / DIM);
    float var = ss * (1.f / DIM) - mu * mu;
    float rs = rsqrtf(var + 1e-6f);

    {
        unsigned wds[16];
#pragma unroll
        for (int g = 0; g < 8; ++g)
#pragma unroll
            for (int pi = 0; pi < 2; ++pi) {
                unsigned wk = ypk[g * 2 + pi];
                float lo = __uint_as_float(wk << 16);
                float hi = __uint_as_float(wk & 0xffff0000u);
                int c0 = g * 16 + t4 * 2 + pi, c1 = c0 + 8;
                lo = (lo - mu) * rs * lng[c0] + lnb[c0];
                hi = (hi - mu) * rs * lng[c1] + lnb[c1];
                wds[g * 2 + pi] = su16(lo) | (su16(hi) << 16);
            }
        // thread's 32 contiguous j's (permuted layout), XOR-swizzled 16B blocks
        __hip_bfloat16* dst = ylds + px * 136 + t4 * 32;
#pragma unroll
        for (int c4 = 0; c4 < 4; ++c4) {
            uint4 vv;
            vv.x = wds[c4 * 4 + 0];
            vv.y = wds[c4 * 4 + 1];
            vv.z = wds[c4 * 4 + 2];
            vv.w = wds[c4 * 4 + 3];
            *(uint4*)&dst[(c4 ^ (px & 3)) << 3] = vv;
        }
    }
    // same wave: ylds visible in-order

    // ---- MLP GEMM1 ----
    bf16x8 ay[4];
#pragma unroll
    for (int ks = 0; ks < 4; ++ks)
        ay[ks] = *(const bf16x8*)&ylds[l15 * 136 + ks * 32 + ((l4 ^ (l15 & 3)) << 3)];

#pragma unroll
    for (int half = 0; half < 2; ++half) {
        f32x4 zac[8];
#pragma unroll
        for (int n = 0; n < 8; ++n) zac[n] = (f32x4){0.f, 0.f, 0.f, 0.f};
#pragma unroll
        for (int ks = 0; ks < 4; ++ks)
#pragma unroll
            for (int n = 0; n < 8; ++n) {
                int nt = half * 8 + n;
                bf16x8 bf = *(const bf16x8*)&mw1b[(nt * 16 + l15) * DIM + ks * 32 + l4 * 8];
                zac[n] = mfma16(ay[ks], bf, zac[n]);
            }
#pragma unroll
        for (int n = 0; n < 8; ++n) {
            int nt = half * 8 + n;
            float bv = mb1[nt * 16 + l15];
#pragma unroll
            for (int r = 0; r < 4; ++r) {
                float v = gelu_t(zac[n][r] + bv);
                zsh[(l4 * 4 + r) * 264 + nt * 16 + l15] = __float2bfloat16(v);
            }
        }
    }

    bf16x8 az[8];
#pragma unroll
    for (int ks = 0; ks < 8; ++ks)
        az[ks] = *(const bf16x8*)&zsh[l15 * 264 + ks * 32 + l4 * 8];

    f32x4 oac[8];
#pragma unroll
    for (int n = 0; n < 8; ++n) oac[n] = (f32x4){0.f, 0.f, 0.f, 0.f};
#pragma unroll
    for (int ks = 0; ks < 8; ++ks)
#pragma unroll
        for (int n = 0; n < 8; ++n) {
            bf16x8 bf = *(const bf16x8*)&mw2b[(n * 16 + l15) * 256 + ks * 32 + l4 * 8];
            oac[n] = mfma16(az[ks], bf, oac[n]);
        }

    float4 xr[8];
#pragma unroll
    for (int n = 0; n < 8; ++n) {
        int c = n * 16 + l15;
        xr[n] = *(const float4*)&x[(((size_t)b * DIM + c) * Hs + h) * Ws + w0 + l4 * 4];
    }
#pragma unroll
    for (int n = 0; n < 8; ++n) {
        int c = n * 16 + l15;
        float bv = mb2[c];
        size_t gi = (((size_t)b * DIM + c) * Hs + h) * Ws + w0 + l4 * 4;
        float4 o;
        o.x = oac[n][0] + bv + xr[n].x;
        o.y = oac[n][1] + bv + xr[n].y;
        o.z = oac[n][2] + bv + xr[n].z;
        o.w = oac[n][3] + bv + xr[n].w;
        *(float4*)&out[gi] = o;
    }
}

extern "C" void kernel_launch(void* const* d_in, const int* in_sizes, int n_in,
                              void* d_out, int out_size, void* d_ws, size_t ws_size,
                              hipStream_t stream) {
    const float* x       = (const float*)d_in[0];
    const float* conv1_w = (const float*)d_in[1];
    const float* conv1_b = (const float*)d_in[2];
    const float* bn_g    = (const float*)d_in[3];
    const float* bn_b    = (const float*)d_in[4];
    const float* bn_mean = (const float*)d_in[5];
    const float* bn_var  = (const float*)d_in[6];
    const float* conv2_w = (const float*)d_in[7];
    const float* conv2_b = (const float*)d_in[8];
    const float* ln_g    = (const float*)d_in[9];
    const float* ln_b    = (const float*)d_in[10];
    const float* pw1_w   = (const float*)d_in[11];
    const float* pw1_b   = (const float*)d_in[12];
    const float* pw2_w   = (const float*)d_in[13];
    const float* pw2_b   = (const float*)d_in[14];
    float* out = (float*)d_out;

    char* ws = (char*)d_ws;
    __hip_bfloat16* w1b  = (__hip_bfloat16*)ws;                   // 8 KB
    __hip_bfloat16* w2b  = (__hip_bfloat16*)(ws + 8192);          // 26 KB
    __hip_bfloat16* mw1b = (__hip_bfloat16*)(ws + 34816);         // 64 KB (K-perm)
    __hip_bfloat16* mw2b = (__hip_bfloat16*)(ws + 100352);        // 64 KB
    unsigned* xpair      = (unsigned*)(ws + (1 << 20));           // 8.4 MB

    hipLaunchKernelGGL(k0_cvt, dim3(2048), dim3(256), 0, stream,
                       conv1_w, conv2_w, pw1_w, pw2_w, x,
                       w1b, w2b, mw1b, mw2b, xpair);
    hipLaunchKernelGGL(k_all, dim3(Bn * Hs * 4), dim3(64), 0, stream,
                       x, xpair, w1b, conv1_b, bn_g, bn_b, bn_mean, bn_var,
                       w2b, conv2_b, ln_g, ln_b,
                       mw1b, pw1_b, mw2b, pw2_b, out);
}